// Round 2
// baseline (587.569 us; speedup 1.0000x reference)
//
#include <hip/hip_runtime.h>
#include <hip/hip_bf16.h>

#define D 64
#define K 3

typedef __hip_bfloat16 bf16;

__device__ __forceinline__ float b2f(bf16 v) { return __bfloat162float(v); }

// Param buffer layout (fp32, in ws):
//   [0,4096)       Wa
//   [4096,4160)    ba
//   [4160,8256)    Wd
//   [8256,8320)    bd
//   [8320,20608)   Wb (3x64x64)
//   [20608,20800)  bb (3x64)
//   [20800,20864)  gamma
//   [20864,20928)  beta
#define P_WA 0
#define P_BA 4096
#define P_WD 4160
#define P_BD 8256
#define P_WB 8320
#define P_BB 20608
#define P_G  20800
#define P_B  20864
#define P_TOTAL 20928

// Detect float dtype from gamma (== ones by construction).
// fp32 ones -> first u32 = 0x3F800000 ; bf16 ones -> 0x3F803F80.
__global__ void detect_kernel(const unsigned int* __restrict__ gamma_raw, int* __restrict__ flag)
{
    *flag = (gamma_raw[0] == 0x3F803F80u) ? 1 : 0;
}

__global__ void cvt_params(const void* Wa, const void* ba, const void* Wd, const void* bd,
                           const void* Wb, const void* bb, const void* g, const void* b,
                           float* __restrict__ P, const int* __restrict__ flag)
{
    const int isbf = *flag;
    int i = blockIdx.x * blockDim.x + threadIdx.x;
    const int stride = gridDim.x * blockDim.x;
    for (; i < P_TOTAL; i += stride) {
        const void* src; int off;
        if (i < P_BA)      { src = Wa; off = i; }
        else if (i < P_WD) { src = ba; off = i - P_BA; }
        else if (i < P_BD) { src = Wd; off = i - P_WD; }
        else if (i < P_WB) { src = bd; off = i - P_BD; }
        else if (i < P_BB) { src = Wb; off = i - P_WB; }
        else if (i < P_G)  { src = bb; off = i - P_BB; }
        else if (i < P_B)  { src = g;  off = i - P_G; }
        else               { src = b;  off = i - P_B; }
        float v;
        if (isbf) v = b2f(((const bf16*)src)[off]);
        else      v = ((const float*)src)[off];
        P[i] = v;
    }
}

// One block computes 4 nodes x 64 outputs for one of 5 linear maps
// (blockIdx.y: 0=Ax, 1=Dx, 2..4=Bx[k] with hop-delayed input layer 2-k).
__global__ void lin_kernel(const void* __restrict__ xs_raw,
                           const float* __restrict__ P, const int* __restrict__ flag,
                           float* __restrict__ Ax, float* __restrict__ Dx,
                           float* __restrict__ Bx, int N)
{
    __shared__ float sw[64][64];   // W[d][o]
    __shared__ float sxr[4][64];
    __shared__ float sbias[64];

    const int which = blockIdx.y;
    const float* W; const float* bias; size_t xbase; float* out;
    if (which == 0)      { W = P + P_WA; bias = P + P_BA; xbase = (size_t)2 * N * D; out = Ax; }
    else if (which == 1) { W = P + P_WD; bias = P + P_BD; xbase = (size_t)2 * N * D; out = Dx; }
    else {
        const int k = which - 2;                 // hop index 0..2
        W = P + P_WB + (size_t)k * D * D;
        bias = P + P_BB + (size_t)k * D;
        const int layer = 2 - k;                 // state_idx = [2,1,0]
        xbase = (size_t)layer * N * D;
        out = Bx + (size_t)k * N * D;
    }

    const int tid = threadIdx.x;
    for (int idx = tid; idx < D * D; idx += 256)
        sw[idx >> 6][idx & 63] = W[idx];
    if (tid < 64) sbias[tid] = bias[tid];

    const int r = tid >> 6, c = tid & 63;
    const int n = blockIdx.x * 4 + r;
    const size_t xoff = xbase + (size_t)n * D + c;
    const int isbf = *flag;
    float xv = 0.f;
    if (n < N) {
        if (isbf) xv = b2f(((const bf16*)xs_raw)[xoff]);
        else      xv = ((const float*)xs_raw)[xoff];
    }
    sxr[r][c] = xv;
    __syncthreads();

    float acc = sbias[c];
    #pragma unroll
    for (int kk = 0; kk < 64; kk++)
        acc += sxr[r][kk] * sw[kk][c];

    if (n < N) out[(size_t)n * D + c] = acc;
}

// One 64-lane group per edge, lane = feature.
__global__ void edge_kernel(const int* __restrict__ ei, const int* __restrict__ ea,
                            const float* __restrict__ Dx, const float* __restrict__ Bx,
                            float* __restrict__ num, float* __restrict__ den,
                            int N, int E)
{
    const long long g = (long long)blockIdx.x * blockDim.x + threadIdx.x;
    const int e = (int)(g >> 6);
    const int d = (int)(g & 63);
    if (e >= E) return;

    const int j  = ei[e];          // source
    const int i  = ei[E + e];      // destination
    const int ke = ea[e] - 1;      // hop 0..2

    const float dx = Dx[(size_t)i * D + d];
    const float bx = Bx[((size_t)ke * N + j) * D + d];
    const float s  = 1.f / (1.f + __expf(-(dx + bx)));

    const size_t seg = ((size_t)i * K + ke) * D + d;
    atomicAdd(&num[seg], s * bx);
    atomicAdd(&den[seg], s);
}

// eta combine + x_new (in place over Ax) + per-feature sum/sumsq partials.
__global__ void combine_kernel(float* __restrict__ Ax,
                               const float* __restrict__ num, const float* __restrict__ den,
                               float* __restrict__ stats, int N)
{
    __shared__ float red[256];
    const int tid = threadIdx.x;
    const int r = tid >> 6, d = tid & 63;

    float lsum = 0.f, lsq = 0.f;
    for (int n = blockIdx.x * 4 + r; n < N; n += gridDim.x * 4) {
        float eta = 0.f;
        #pragma unroll
        for (int k = 0; k < K; k++) {
            const size_t idx = ((size_t)n * K + k) * D + d;
            eta += num[idx] / (den[idx] + 1e-6f);
        }
        const size_t xi = (size_t)n * D + d;
        const float v = Ax[xi] + eta * (1.f / 3.f);
        Ax[xi] = v;
        lsum += v;
        lsq  += v * v;
    }

    red[tid] = lsum;
    __syncthreads();
    if (tid < 64) atomicAdd(&stats[d], red[d] + red[64 + d] + red[128 + d] + red[192 + d]);
    __syncthreads();
    red[tid] = lsq;
    __syncthreads();
    if (tid < 64) atomicAdd(&stats[64 + d], red[d] + red[64 + d] + red[128 + d] + red[192 + d]);
}

// BatchNorm (training-mode batch stats, biased var) + ReLU + store (dtype per flag).
__global__ void finalize_kernel(const float* __restrict__ xnew, const float* __restrict__ stats,
                                const float* __restrict__ P, const int* __restrict__ flag,
                                void* __restrict__ out, int N)
{
    const long long g = (long long)blockIdx.x * blockDim.x + threadIdx.x;
    if (g >= (long long)N * D) return;
    const int d = (int)(g & 63);

    const float invN = 1.f / (float)N;
    const float mean = stats[d] * invN;
    const float var  = stats[64 + d] * invN - mean * mean;
    const float rstd = rsqrtf(var + 1e-5f);

    float y = P[P_G + d] * (xnew[g] - mean) * rstd + P[P_B + d];
    y = fmaxf(y, 0.f);

    if (*flag) ((bf16*)out)[g] = __float2bfloat16(y);
    else       ((float*)out)[g] = y;
}

extern "C" void kernel_launch(void* const* d_in, const int* in_sizes, int n_in,
                              void* d_out, int out_size, void* d_ws, size_t ws_size,
                              hipStream_t stream)
{
    const void* xs    = d_in[0];
    const int*  ei    = (const int*)d_in[1];
    const int*  ea    = (const int*)d_in[2];

    const int N = in_sizes[0] / (3 * D);   // xs is [T+1=3, N, D]
    const int E = in_sizes[2];

    float* ws = (float*)d_ws;
    const size_t nd = (size_t)N * D;
    float* Ax    = ws;                 // [N,64]  (reused as x_new)
    float* Dx    = Ax + nd;            // [N,64]
    float* Bx    = Dx + nd;            // [3,N,64]
    float* num   = Bx + 3 * nd;        // [N,3,64]
    float* den   = num + 3 * nd;       // [N,3,64]
    float* stats = den + 3 * nd;       // [128]: sum, sumsq
    float* P     = stats + 128;        // [P_TOTAL] fp32 params
    int*   flag  = (int*)(P + P_TOTAL);

    // zero num, den, stats in one shot (contiguous)
    hipMemsetAsync(num, 0, (6 * nd + 128) * sizeof(float), stream);

    detect_kernel<<<1, 1, 0, stream>>>((const unsigned int*)d_in[9], flag);

    cvt_params<<<82, 256, 0, stream>>>(d_in[3], d_in[4], d_in[5], d_in[6],
                                       d_in[7], d_in[8], d_in[9], d_in[10], P, flag);

    dim3 lgrid((N + 3) / 4, 5);
    lin_kernel<<<lgrid, 256, 0, stream>>>(xs, P, flag, Ax, Dx, Bx, N);

    const long long ethreads = (long long)E * 64;
    edge_kernel<<<(int)((ethreads + 255) / 256), 256, 0, stream>>>(ei, ea, Dx, Bx, num, den, N, E);

    combine_kernel<<<512, 256, 0, stream>>>(Ax, num, den, stats, N);

    const long long oel = (long long)N * D;
    finalize_kernel<<<(int)((oel + 255) / 256), 256, 0, stream>>>(Ax, stats, P, flag, d_out, N);
}

// Round 3
// 354.876 us; speedup vs baseline: 1.6557x; 1.6557x over previous
//
#include <hip/hip_runtime.h>
#include <hip/hip_bf16.h>

#define D 64
#define K 3

typedef __hip_bfloat16 bf16;

__device__ __forceinline__ float b2f(bf16 v) { return __bfloat162float(v); }

// Param buffer layout (fp32, in ws):
#define P_WA 0
#define P_BA 4096
#define P_WD 4160
#define P_BD 8256
#define P_WB 8320
#define P_BB 20608
#define P_G  20800
#define P_B  20864
#define P_TOTAL 20928

// Detect float dtype from gamma (== ones by construction).
// fp32 ones -> first u32 = 0x3F800000 ; bf16 ones -> 0x3F803F80.
__global__ void detect_kernel(const unsigned int* __restrict__ gamma_raw, int* __restrict__ flag)
{
    *flag = (gamma_raw[0] == 0x3F803F80u) ? 1 : 0;
}

__global__ void cvt_params(const void* Wa, const void* ba, const void* Wd, const void* bd,
                           const void* Wb, const void* bb, const void* g, const void* b,
                           float* __restrict__ P, const int* __restrict__ flag)
{
    const int isbf = *flag;
    int i = blockIdx.x * blockDim.x + threadIdx.x;
    const int stride = gridDim.x * blockDim.x;
    for (; i < P_TOTAL; i += stride) {
        const void* src; int off;
        if (i < P_BA)      { src = Wa; off = i; }
        else if (i < P_WD) { src = ba; off = i - P_BA; }
        else if (i < P_BD) { src = Wd; off = i - P_WD; }
        else if (i < P_WB) { src = bd; off = i - P_BD; }
        else if (i < P_BB) { src = Wb; off = i - P_WB; }
        else if (i < P_G)  { src = bb; off = i - P_BB; }
        else if (i < P_B)  { src = g;  off = i - P_G; }
        else               { src = b;  off = i - P_B; }
        float v;
        if (isbf) v = b2f(((const bf16*)src)[off]);
        else      v = ((const float*)src)[off];
        P[i] = v;
    }
}

// Persistent linear: blockIdx.y selects map (0=Ax,1=Dx,2..4=Bx[k]); weights
// loaded into LDS ONCE per block, then grid-stride over nodes (4 nodes/iter).
__global__ void lin_kernel(const void* __restrict__ xs_raw,
                           const float* __restrict__ P, const int* __restrict__ flag,
                           float* __restrict__ Ax, float* __restrict__ Dx,
                           float* __restrict__ Bx, int N)
{
    __shared__ float sw[64][64];
    __shared__ float sxr[4][64];
    __shared__ float sbias[64];

    const int which = blockIdx.y;
    const float* W; const float* bias; size_t xbase; float* out;
    if (which == 0)      { W = P + P_WA; bias = P + P_BA; xbase = (size_t)2 * N * D; out = Ax; }
    else if (which == 1) { W = P + P_WD; bias = P + P_BD; xbase = (size_t)2 * N * D; out = Dx; }
    else {
        const int k = which - 2;
        W = P + P_WB + (size_t)k * D * D;
        bias = P + P_BB + (size_t)k * D;
        const int layer = 2 - k;                 // state_idx = [2,1,0]
        xbase = (size_t)layer * N * D;
        out = Bx + (size_t)k * N * D;
    }

    const int tid = threadIdx.x;
    for (int idx = tid; idx < D * D; idx += 256)
        sw[idx >> 6][idx & 63] = W[idx];
    if (tid < 64) sbias[tid] = bias[tid];

    const int r = tid >> 6, c = tid & 63;
    const int isbf = *flag;
    const int stride = gridDim.x * 4;

    for (int n0 = blockIdx.x * 4; n0 < N; n0 += stride) {
        const int n = n0 + r;
        float xv = 0.f;
        if (n < N) {
            const size_t xoff = xbase + (size_t)n * D + c;
            if (isbf) xv = b2f(((const bf16*)xs_raw)[xoff]);
            else      xv = ((const float*)xs_raw)[xoff];
        }
        __syncthreads();
        sxr[r][c] = xv;
        __syncthreads();

        float acc = sbias[c];
        #pragma unroll
        for (int kk = 0; kk < 64; kk++)
            acc += sxr[r][kk] * sw[kk][c];

        if (n < N) out[(size_t)n * D + c] = acc;
    }
}

// ---- CSR build (counting sort by destination node) ----
__global__ void count_kernel(const int* __restrict__ ei, int* __restrict__ cnt, int E)
{
    const int e = blockIdx.x * blockDim.x + threadIdx.x;
    if (e < E) atomicAdd(&cnt[ei[E + e]], 1);
}

__global__ void scan1_kernel(int* __restrict__ cnt, int* __restrict__ btot, int N)
{
    __shared__ int s[256];
    const int t = threadIdx.x;
    const int i = blockIdx.x * 256 + t;
    const int v = (i < N) ? cnt[i] : 0;
    s[t] = v;
    __syncthreads();
    #pragma unroll
    for (int o = 1; o < 256; o <<= 1) {
        int x = (t >= o) ? s[t - o] : 0;
        __syncthreads();
        s[t] += x;
        __syncthreads();
    }
    if (i < N) cnt[i] = s[t] - v;          // exclusive within block
    if (t == 255) btot[blockIdx.x] = s[t]; // block total
}

__global__ void scan2_kernel(int* __restrict__ btot, int* __restrict__ boff, int nb)
{
    __shared__ int s[256];
    const int t = threadIdx.x;
    const int v = (t < nb) ? btot[t] : 0;
    s[t] = v;
    __syncthreads();
    #pragma unroll
    for (int o = 1; o < 256; o <<= 1) {
        int x = (t >= o) ? s[t - o] : 0;
        __syncthreads();
        s[t] += x;
        __syncthreads();
    }
    if (t < nb) boff[t] = s[t] - v;        // exclusive
}

__global__ void scan3_kernel(int* __restrict__ cnt, const int* __restrict__ boff, int N, int E)
{
    const int i = blockIdx.x * blockDim.x + threadIdx.x;
    if (i < N) cnt[i] += boff[i >> 8];
    if (i == 0) cnt[N] = E;
}

__global__ void scatter_kernel(const int* __restrict__ ei, const int* __restrict__ ea,
                               const int* __restrict__ off, int* __restrict__ cur,
                               int* __restrict__ elist, int E)
{
    const int e = blockIdx.x * blockDim.x + threadIdx.x;
    if (e >= E) return;
    const int j  = ei[e];
    const int i  = ei[E + e];
    const int ke = ea[e] - 1;
    const int pos = atomicAdd(&cur[i], 1);
    elist[off[i] + pos] = (j << 2) | ke;
}

// ---- fused segment-reduce + eta + x_new + BN partials ----
// One wave per node; lane = feature. num/den per hop held in registers.
__global__ void node_kernel(float* __restrict__ Ax,            // read, overwritten with x_new
                            const float* __restrict__ Dx, const float* __restrict__ Bx,
                            const int* __restrict__ off, const int* __restrict__ elist,
                            float* __restrict__ statsP, int N)
{
    __shared__ float red[256];
    const int tid = threadIdx.x;
    const int w = tid >> 6, d = tid & 63;

    float lsum = 0.f, lsq = 0.f;
    for (int n = blockIdx.x * 4 + w; n < N; n += gridDim.x * 4) {
        const float dx = Dx[(size_t)n * D + d];
        float num0 = 0.f, num1 = 0.f, num2 = 0.f;
        float den0 = 0.f, den1 = 0.f, den2 = 0.f;
        const int start = off[n], end = off[n + 1];

        for (int base = start; base < end; base += 64) {
            int m = end - base; if (m > 64) m = 64;
            const int li = base + d;
            const int val = (li < end) ? elist[li] : 0;
            int c = 0;
            for (; c + 1 < m; c += 2) {
                const int v0 = __shfl(val, c, 64);
                const int v1 = __shfl(val, c + 1, 64);
                const int ke0 = v0 & 3, j0 = v0 >> 2;
                const int ke1 = v1 & 3, j1 = v1 >> 2;
                const float bx0 = Bx[((size_t)ke0 * N + j0) * D + d];
                const float bx1 = Bx[((size_t)ke1 * N + j1) * D + d];
                const float s0 = 1.f / (1.f + __expf(-(dx + bx0)));
                const float s1 = 1.f / (1.f + __expf(-(dx + bx1)));
                num0 += (ke0 == 0) ? s0 * bx0 : 0.f; den0 += (ke0 == 0) ? s0 : 0.f;
                num1 += (ke0 == 1) ? s0 * bx0 : 0.f; den1 += (ke0 == 1) ? s0 : 0.f;
                num2 += (ke0 == 2) ? s0 * bx0 : 0.f; den2 += (ke0 == 2) ? s0 : 0.f;
                num0 += (ke1 == 0) ? s1 * bx1 : 0.f; den0 += (ke1 == 0) ? s1 : 0.f;
                num1 += (ke1 == 1) ? s1 * bx1 : 0.f; den1 += (ke1 == 1) ? s1 : 0.f;
                num2 += (ke1 == 2) ? s1 * bx1 : 0.f; den2 += (ke1 == 2) ? s1 : 0.f;
            }
            if (c < m) {
                const int v0 = __shfl(val, c, 64);
                const int ke0 = v0 & 3, j0 = v0 >> 2;
                const float bx0 = Bx[((size_t)ke0 * N + j0) * D + d];
                const float s0 = 1.f / (1.f + __expf(-(dx + bx0)));
                num0 += (ke0 == 0) ? s0 * bx0 : 0.f; den0 += (ke0 == 0) ? s0 : 0.f;
                num1 += (ke0 == 1) ? s0 * bx0 : 0.f; den1 += (ke0 == 1) ? s0 : 0.f;
                num2 += (ke0 == 2) ? s0 * bx0 : 0.f; den2 += (ke0 == 2) ? s0 : 0.f;
            }
        }

        const float eta = num0 / (den0 + 1e-6f) + num1 / (den1 + 1e-6f) + num2 / (den2 + 1e-6f);
        const size_t xi = (size_t)n * D + d;
        const float v = Ax[xi] + eta * (1.f / 3.f);
        Ax[xi] = v;
        lsum += v;
        lsq  += v * v;
    }

    red[tid] = lsum;
    __syncthreads();
    if (tid < 64) {
        float* sp = statsP + (size_t)(blockIdx.x & 63) * 128;
        atomicAdd(&sp[d], red[d] + red[64 + d] + red[128 + d] + red[192 + d]);
    }
    __syncthreads();
    red[tid] = lsq;
    __syncthreads();
    if (tid < 64) {
        float* sp = statsP + (size_t)(blockIdx.x & 63) * 128;
        atomicAdd(&sp[64 + d], red[d] + red[64 + d] + red[128 + d] + red[192 + d]);
    }
}

// Sum the 64 contention-spread stat copies -> stats[128].
__global__ void bnreduce_kernel(const float* __restrict__ statsP, float* __restrict__ stats)
{
    const int t = threadIdx.x;   // 0..127
    float a = 0.f;
    for (int c = 0; c < 64; c++) a += statsP[c * 128 + t];
    stats[t] = a;
}

// BatchNorm (training-mode batch stats, biased var) + ReLU + store (dtype per flag).
__global__ void finalize_kernel(const float* __restrict__ xnew, const float* __restrict__ stats,
                                const float* __restrict__ P, const int* __restrict__ flag,
                                void* __restrict__ out, int N)
{
    const long long g = (long long)blockIdx.x * blockDim.x + threadIdx.x;
    if (g >= (long long)N * D) return;
    const int d = (int)(g & 63);

    const float invN = 1.f / (float)N;
    const float mean = stats[d] * invN;
    const float var  = stats[64 + d] * invN - mean * mean;
    const float rstd = rsqrtf(var + 1e-5f);

    float y = P[P_G + d] * (xnew[g] - mean) * rstd + P[P_B + d];
    y = fmaxf(y, 0.f);

    if (*flag) ((bf16*)out)[g] = __float2bfloat16(y);
    else       ((float*)out)[g] = y;
}

extern "C" void kernel_launch(void* const* d_in, const int* in_sizes, int n_in,
                              void* d_out, int out_size, void* d_ws, size_t ws_size,
                              hipStream_t stream)
{
    const void* xs = d_in[0];
    const int*  ei = (const int*)d_in[1];
    const int*  ea = (const int*)d_in[2];

    const int N = in_sizes[0] / (3 * D);   // xs is [3, N, D]
    const int E = in_sizes[2];

    float* ws = (float*)d_ws;
    const size_t nd = (size_t)N * D;

    float* P      = ws;                       // [P_TOTAL]
    int*   flag   = (int*)(P + P_TOTAL);      // [1]
    float* Ax     = (float*)(flag + 1);       // [N,64] -> becomes x_new
    float* Dx     = Ax + nd;                  // [N,64]
    float* Bx     = Dx + nd;                  // [3,N,64]
    float* statsP = Bx + 3 * nd;              // [64*128]  (zeroed)
    float* stats  = statsP + 64 * 128;        // [128]
    int*   cnt    = (int*)(stats + 128);      // [N+1] -> becomes off (zeroed)
    int*   cur    = cnt + (N + 1);            // [N]   (zeroed)
    int*   btot   = cur + N;                  // [256] (zeroed)
    int*   boff   = btot + 256;               // [256] (zeroed)
    int*   elist  = boff + 256;               // [E]

    // zero statsP..boff in one shot (contiguous)
    const size_t zbytes = (size_t)(64 * 128 + 128) * 4 + ((size_t)(N + 1) + N + 512) * 4;
    hipMemsetAsync(statsP, 0, zbytes, stream);

    detect_kernel<<<1, 1, 0, stream>>>((const unsigned int*)d_in[9], flag);
    cvt_params<<<82, 256, 0, stream>>>(d_in[3], d_in[4], d_in[5], d_in[6],
                                       d_in[7], d_in[8], d_in[9], d_in[10], P, flag);

    dim3 lgrid(512, 5);
    lin_kernel<<<lgrid, 256, 0, stream>>>(xs, P, flag, Ax, Dx, Bx, N);

    const int eblocks = (E + 255) / 256;
    count_kernel<<<eblocks, 256, 0, stream>>>(ei, cnt, E);

    const int nb = (N + 255) / 256;           // <= 256 required (N<=65536)
    scan1_kernel<<<nb, 256, 0, stream>>>(cnt, btot, N);
    scan2_kernel<<<1, 256, 0, stream>>>(btot, boff, nb);
    scan3_kernel<<<(N + 256) / 256, 256, 0, stream>>>(cnt, boff, N, E);

    scatter_kernel<<<eblocks, 256, 0, stream>>>(ei, ea, cnt, cur, elist, E);

    node_kernel<<<(N + 3) / 4, 256, 0, stream>>>(Ax, Dx, Bx, cnt, elist, statsP, N);

    bnreduce_kernel<<<1, 128, 0, stream>>>(statsP, stats);

    finalize_kernel<<<(int)((nd + 255) / 256), 256, 0, stream>>>(Ax, stats, P, flag, d_out, N);
}